// Round 5
// baseline (231.191 us; speedup 1.0000x reference)
//
#include <hip/hip_runtime.h>

#define K 64
#define S_CHUNK 128
#define W_BURN 160
#define BATCH 16

typedef __attribute__((ext_vector_type(4))) _Float16 half4;
typedef __attribute__((ext_vector_type(4))) float f32x4;

__device__ __forceinline__ float waveReduceSum(float v) {
#pragma unroll
    for (int off = 32; off > 0; off >>= 1) v += __shfl_xor(v, off, 64);
    return v;
}

// ws layout (float offsets)
#define WS_P     0      // P row-major [64][64] f32
#define WS_PI    4096
#define WS_UTT0  4160
#define WS_ISG   4224   // 1/sigma
#define WS_NNU   4288   // -mu/sigma
#define WS_L2N   4352   // log2(1/(sigma*sqrt(2pi)))

__global__ __launch_bounds__(64) void hmm_setup(
    const float* __restrict__ y, const float* __restrict__ logits,
    const float* __restrict__ mu, const float* __restrict__ log_sigma,
    float* __restrict__ out, float* __restrict__ ws, int T)
{
    __shared__ float P[K][K];
    __shared__ float pib[K];
    const int k = threadIdx.x;

    float row[K]; float m = -3.4e38f;
#pragma unroll
    for (int i = 0; i < K; ++i) { row[i] = logits[k*K + i]; m = fmaxf(m, row[i]); }
    float s = 0.f;
#pragma unroll
    for (int i = 0; i < K; ++i) { row[i] = __expf(row[i] - m); s += row[i]; }
    float inv = 1.0f / s;
#pragma unroll
    for (int i = 0; i < K; ++i) { float p = row[i]*inv; P[k][i] = p; ws[WS_P + k*K + i] = p; }
    __syncthreads();

    pib[k] = 1.0f/64.0f;
    __syncthreads();
    for (int it = 0; it < 64; ++it) {
        float acc = 0.f;
#pragma unroll
        for (int j = 0; j < K; ++j) acc += pib[j]*P[j][k];   // (pi^T P)_k
        float tot = waveReduceSum(acc);
        acc /= tot;
        __syncthreads();
        pib[k] = acc;
        __syncthreads();
    }
    float pi_k = pib[k];

    float mu_k = mu[k];
    float isg = __expf(-log_sigma[k]);            // 1/sigma
    float inorm = isg * 0.39894228040143267f;     // 1/(sigma*sqrt(2pi))

    ws[WS_PI  + k] = pi_k;
    ws[WS_ISG + k] = isg;
    ws[WS_NNU + k] = -mu_k * isg;
    ws[WS_L2N + k] = __log2f(inorm);

    float y0 = y[0];
    float z = (y0 - mu_k) * isg;
    float g0 = __expf(-0.5f*z*z) * inorm;
    float num = pi_k * g0;
    float ft0 = waveReduceSum(num);
    float utt0 = num / ft0;
    ws[WS_UTT0 + k] = utt0;

    out[k] = pi_k;                       // ut[0]
    out[(size_t)T*K + k] = utt0;         // unorm[0]
    if (k == 0) out[(size_t)2*T*K] = ft0;// ft[0]
}

// One wave = 16 chunks (MFMA columns), software-pipelined with LAGGED
// power-of-2 normalization: beta stays unnormalized f16; step t's emission
// is scaled by 2^-E(st_{t-1}) folded into the exp2 argument. The reduce,
// rcp's and all output stores lag one step, issuing under the next step's
// MFMA window. Critical chain per step: MFMA(2-deep split) -> g*acc -> cvt.
__global__ __launch_bounds__(64) void hmm_scan(
    const float* __restrict__ y, const float* __restrict__ ws,
    float* __restrict__ out, int T)
{
    const int lane = threadIdx.x;
    const int c = lane & 15;          // chunk slot / matrix column
    const int q = lane >> 4;          // lane group
    const int NCH = (T + S_CHUNK - 1) / S_CHUNK;
    (void)NCH;
    const int cg = blockIdx.x * BATCH + c;
    const int t0 = cg * S_CHUNK;

    // A fragments: A(nb,kb)[i][kk] = P[16kb+kk][16nb+i]
    half4 a[4][4];
#pragma unroll
    for (int nb = 0; nb < 4; ++nb)
#pragma unroll
        for (int kb = 0; kb < 4; ++kb)
#pragma unroll
            for (int j = 0; j < 4; ++j)
                a[nb][kb][j] = (_Float16)ws[WS_P + (16*kb + 4*q + j)*K + 16*nb + c];

    f32x4 isg_[4], nnu_[4], l2n_[4];
#pragma unroll
    for (int nb = 0; nb < 4; ++nb)
#pragma unroll
        for (int r = 0; r < 4; ++r) {
            int s = 16*nb + 4*q + r;
            isg_[nb][r] = ws[WS_ISG + s];
            nnu_[nb][r] = ws[WS_NNU + s];
            l2n_[nb][r] = ws[WS_L2N + s];
        }

    half4 bfr[4], u0h[4];
#pragma unroll
    for (int kb = 0; kb < 4; ++kb)
#pragma unroll
        for (int j = 0; j < 4; ++j) {
            int s = 16*kb + 4*q + j;
            bfr[kb][j] = (_Float16)ws[WS_PI + s];
            u0h[kb][j] = (_Float16)ws[WS_UTT0 + s];
        }

    const int tlo = (cg == 0) ? 1 : 0;
    int tcur = t0 - W_BURN;

    float* po = out + (size_t)t0 * K + 4*q;
    float* pu = po + (size_t)T * K;
    float* pf = out + (size_t)2 * T * K + t0;

    // pipeline state: h = in-lane partial sum of nb_{t-1}; rmP = rcp(mant(st_{t-2}))
    float h = 0.25f;      // finalizes to st = 1 (beta = pi, sum 1)
    float rmP = 1.0f;
    f32x4 nbP[4] = {{0.f,0.f,0.f,0.f},{0.f,0.f,0.f,0.f},
                    {0.f,0.f,0.f,0.f},{0.f,0.f,0.f,0.f}};

    int ib = min(max(tcur, 0), T - 4);
    f32x4 yv = *(const f32x4*)(y + ib);

#define STEP(OUTC, OUTPV, YCUR) do {                                           \
    /* 1. MFMA, depth-2 via split accumulators */                              \
    f32x4 accA_[4] = {{0.f,0.f,0.f,0.f},{0.f,0.f,0.f,0.f},                     \
                      {0.f,0.f,0.f,0.f},{0.f,0.f,0.f,0.f}};                    \
    f32x4 accB_[4] = {{0.f,0.f,0.f,0.f},{0.f,0.f,0.f,0.f},                     \
                      {0.f,0.f,0.f,0.f},{0.f,0.f,0.f,0.f}};                    \
    _Pragma("unroll")                                                          \
    for (int nb_ = 0; nb_ < 4; ++nb_)                                          \
        accA_[nb_] = __builtin_amdgcn_mfma_f32_16x16x16f16(a[nb_][0], bfr[0], accA_[nb_], 0,0,0); \
    _Pragma("unroll")                                                          \
    for (int nb_ = 0; nb_ < 4; ++nb_)                                          \
        accB_[nb_] = __builtin_amdgcn_mfma_f32_16x16x16f16(a[nb_][2], bfr[2], accB_[nb_], 0,0,0); \
    _Pragma("unroll")                                                          \
    for (int nb_ = 0; nb_ < 4; ++nb_)                                          \
        accA_[nb_] = __builtin_amdgcn_mfma_f32_16x16x16f16(a[nb_][1], bfr[1], accA_[nb_], 0,0,0); \
    _Pragma("unroll")                                                          \
    for (int nb_ = 0; nb_ < 4; ++nb_)                                          \
        accB_[nb_] = __builtin_amdgcn_mfma_f32_16x16x16f16(a[nb_][3], bfr[3], accB_[nb_], 0,0,0); \
    /* 2. lag-finalize st_{t-1} (shuffles overlap MFMA) */                     \
    float s1_ = h + __shfl_xor(h, 16, 64);                                     \
    float stP_ = s1_ + __shfl_xor(s1_, 32, 64);                                \
    float rsP_ = __builtin_amdgcn_rcpf(stP_);                                  \
    float ftprev_ = stP_ * rmP;                                                \
    unsigned ub_ = __float_as_uint(stP_);                                      \
    float xf_ = (float)(127 - (int)((ub_ >> 23) & 255u));                      \
    float mant_ = __uint_as_float((ub_ & 0x007fffffu) | 0x3f800000u);          \
    float rmN_ = __builtin_amdgcn_rcpf(mant_);                                 \
    /* 3. emissions with folded 2^xf scale (independent of MFMA) */            \
    f32x4 g_[4];                                                               \
    _Pragma("unroll")                                                          \
    for (int nb_ = 0; nb_ < 4; ++nb_) {                                        \
        f32x4 z_ = YCUR * isg_[nb_] + nnu_[nb_];                               \
        f32x4 ag_ = z_*z_*(-0.72134752f) + l2n_[nb_] + xf_;                    \
        _Pragma("unroll")                                                      \
        for (int r_ = 0; r_ < 4; ++r_) g_[nb_][r_] = __builtin_amdgcn_exp2f(ag_[r_]); \
    }                                                                          \
    /* 4. lagged stores: unorm_{t-1}, ft_{t-1} */                              \
    if (OUTPV) {                                                               \
        const bool pp_ = ((tcur-1) >= tlo) & ((tcur-1) < T);                   \
        if (pp_) {                                                             \
            _Pragma("unroll")                                                  \
            for (int nb_ = 0; nb_ < 4; ++nb_)                                  \
                *(f32x4*)(pu - K + 16*nb_) = nbP[nb_] * rsP_;                  \
            if (lane < 16) pf[-1] = ftprev_;                                   \
        }                                                                      \
    }                                                                          \
    /* 5. chain: acc -> nb -> cvt */                                           \
    f32x4 acc_[4], nbv_[4];                                                    \
    _Pragma("unroll")                                                          \
    for (int nb_ = 0; nb_ < 4; ++nb_) acc_[nb_] = accA_[nb_] + accB_[nb_];     \
    _Pragma("unroll")                                                          \
    for (int nb_ = 0; nb_ < 4; ++nb_) nbv_[nb_] = acc_[nb_] * g_[nb_];         \
    _Pragma("unroll")                                                          \
    for (int kb_ = 0; kb_ < 4; ++kb_) {                                        \
        auto lo_ = __builtin_amdgcn_cvt_pkrtz(nbv_[kb_][0], nbv_[kb_][1]);     \
        auto hi_ = __builtin_amdgcn_cvt_pkrtz(nbv_[kb_][2], nbv_[kb_][3]);     \
        bfr[kb_][0] = (_Float16)lo_[0]; bfr[kb_][1] = (_Float16)lo_[1];        \
        bfr[kb_][2] = (_Float16)hi_[0]; bfr[kb_][3] = (_Float16)hi_[1];        \
    }                                                                          \
    /* 6. current ut store (off-chain) */                                      \
    if (OUTC) {                                                                \
        const bool pc_ = (tcur >= tlo) & (tcur < T);                           \
        if (pc_) {                                                             \
            _Pragma("unroll")                                                  \
            for (int nb_ = 0; nb_ < 4; ++nb_)                                  \
                *(f32x4*)(po + 16*nb_) = acc_[nb_] * rsP_;                     \
        }                                                                      \
    }                                                                          \
    /* 7. in-lane tree partial sum for st_t (finalized next step) */           \
    {                                                                          \
        f32x4 sA_ = nbv_[0] + nbv_[1];                                         \
        f32x4 sB_ = nbv_[2] + nbv_[3];                                         \
        f32x4 sC_ = sA_ + sB_;                                                 \
        h = (sC_[0] + sC_[1]) + (sC_[2] + sC_[3]);                             \
    }                                                                          \
    nbP[0]=nbv_[0]; nbP[1]=nbv_[1]; nbP[2]=nbv_[2]; nbP[3]=nbv_[3];            \
    rmP = rmN_;                                                                \
    if (OUTC) { po += K; pu += K; pf += 1; }                                   \
    ++tcur;                                                                    \
} while (0)

    // burn-in: no stores, lag-scale machinery active
#pragma unroll 1
    for (int gi = 0; gi < W_BURN/4; ++gi) {
        int ibn = min(max(tcur + 4, 0), T - 4);
        f32x4 yn = *(const f32x4*)(y + ibn);
        STEP(0,0, yv[0]); STEP(0,0, yv[1]); STEP(0,0, yv[2]); STEP(0,0, yv[3]);
        yv = yn;
    }
    // first output group (peeled: chunk-0 state override after its t=0 step)
    {
        int ibn = min(max(tcur + 4, 0), T - 4);
        f32x4 yn = *(const f32x4*)(y + ibn);
        STEP(1,0, yv[0]);
        if (cg == 0) {
            bfr[0]=u0h[0]; bfr[1]=u0h[1]; bfr[2]=u0h[2]; bfr[3]=u0h[3];
            h = 0.25f;   // st_0 finalizes to 1 (utt0 sums to 1)
        }
        STEP(1,1, yv[1]); STEP(1,1, yv[2]); STEP(1,1, yv[3]);
        yv = yn;
    }
#pragma unroll 1
    for (int gi = 1; gi < S_CHUNK/4; ++gi) {
        int ibn = min(max(tcur + 4, 0), T - 4);
        f32x4 yn = *(const f32x4*)(y + ibn);
        STEP(1,1, yv[0]); STEP(1,1, yv[1]); STEP(1,1, yv[2]); STEP(1,1, yv[3]);
        yv = yn;
    }
#undef STEP

    // epilogue: finalize + store unorm/ft of the last step
    {
        float s1 = h + __shfl_xor(h, 16, 64);
        float stL = s1 + __shfl_xor(s1, 32, 64);
        float rsL = __builtin_amdgcn_rcpf(stL);
        float ftL = stL * rmP;
        const bool pp = ((tcur-1) >= tlo) & ((tcur-1) < T);
        if (pp) {
#pragma unroll
            for (int nb = 0; nb < 4; ++nb)
                *(f32x4*)(pu - K + 16*nb) = nbP[nb] * rsL;
            if (lane < 16) pf[-1] = ftL;
        }
    }
}

extern "C" void kernel_launch(void* const* d_in, const int* in_sizes, int n_in,
                              void* d_out, int out_size, void* d_ws, size_t ws_size,
                              hipStream_t stream) {
    const float* y      = (const float*)d_in[0];
    const float* logits = (const float*)d_in[1];
    const float* mu     = (const float*)d_in[2];
    const float* lsig   = (const float*)d_in[3];
    float* out = (float*)d_out;
    float* ws  = (float*)d_ws;
    const int T = in_sizes[0];

    hmm_setup<<<1, 64, 0, stream>>>(y, logits, mu, lsig, out, ws, T);

    const int nch  = (T + S_CHUNK - 1) / S_CHUNK;
    const int nblk = (nch + BATCH - 1) / BATCH;
    hmm_scan<<<nblk, 64, 0, stream>>>(y, ws, out, T);
}